// Round 5
// baseline (4048.494 us; speedup 1.0000x reference)
//
// LSTMDecoder on MI355X — round 12: cut launches/step 3 -> 2 (kB+kC fused, R9 failures fixed).
//
// Journal:
// * R2: multi-kernel PASSED 0.0117 @ 9763us. R3-R6: barrier/coop designs failed -> abandoned.
// * R7 (6627us): gemm8 VGPR=32 -> per-MFMA vmcnt serialization diagnosed.
// * R8 (4615us): depth-4 register prefetch everywhere; loop kernels ~2x.
// * R9 (7230us REGRESSION): kBC fusion with 128 blocks + serial dep-load loops. Reverted.
// * R10 (3290us): kA m-split to 256 blocks. All loop kernels <40us (below harness fills).
// * R11 (3203us, prediction MISSED): TLP+chain halving in kA/kB/kC bought only 2.6%.
//   => per-step ~60us is NOT in-kernel latency. Arithmetic: kernels ~5-8us each real work;
//   closes only if inter-kernel overhead ~12-15us/launch. Launch-gap-dominated regime.
// * R12 (this): kB+kC -> kBC-v2, 2 launches/step. R9 failure modes fixed:
//   256 blocks (b x quarter, full CU coverage); enc_comb TRANSPOSED at setup (ecbt[j][bl],
//   gemm_lds with A/B swapped — same FLOPs) so gather = 16 contiguous h16x8 loads, 4 chains;
//   hw = contiguous wcomb-row walk, 4 chains, h2 in LDS; e-dots = R8-proven 4-l groups.
//   Kills ebuf/hwb round-trips. kA/gemm_lds unchanged (R11-proven).
// * Numerics: fp16 MFMA fp32-acc, c-state fp32, fp32 h2f for e-dot. Gather/hw are fp32
//   reorders of identical products (proven-tolerance schedule).

#include <hip/hip_runtime.h>

static constexpr int Bn = 64, Ln = 128, Tn = 48, En = 512, HEn = 1024, Hn = 1024, Gn = 4096;

typedef _Float16 h16;
typedef __attribute__((ext_vector_type(8))) _Float16 h16x8;
typedef __attribute__((ext_vector_type(2))) _Float16 h16x2;
typedef __attribute__((ext_vector_type(4))) float f32x4;

__device__ __forceinline__ float sigf(float x){ return 1.f / (1.f + expf(-x)); }

__device__ __forceinline__ float dot8f(h16x8 a, h16x8 b){
  float s = 0.f;
  #pragma unroll
  for (int i = 0; i < 8; i++) s += (float)a[i] * (float)b[i];
  return s;
}

// ---------------- fp32 -> fp16 conversion ----------------
__global__ void cvt2(const float* __restrict__ in, h16x2* __restrict__ out, int n2){
  int i = blockIdx.x * blockDim.x + threadIdx.x;
  int stride = gridDim.x * blockDim.x;
  for (; i < n2; i += stride){
    float2 v = reinterpret_cast<const float2*>(in)[i];
    h16x2 o; o.x = (h16)v.x; o.y = (h16)v.y;
    out[i] = o;
  }
}

// ---------------- state init ----------------
__global__ void init_state(const float* __restrict__ h1i, const float* __restrict__ c1i,
                           const float* __restrict__ h2i, const float* __restrict__ c2i,
                           h16* __restrict__ h1a, float* __restrict__ c1,
                           h16* __restrict__ h2a, float* __restrict__ c2,
                           float* __restrict__ h2f, h16* __restrict__ oh){
  int i = blockIdx.x * blockDim.x + threadIdx.x;
  if (i < Bn * Hn){
    h1a[i] = (h16)h1i[i]; c1[i] = c1i[i];
    h2a[i] = (h16)h2i[i]; c2[i] = c2i[i];
    h2f[i] = h2i[i];
    oh[i] = (h16)0.f;
  }
}

// ---------------- gemm_lds: 128x128 tile, BK=32, double-buffered LDS ----------------
__global__ __launch_bounds__(256, 2) void gemm_lds(
    const h16* __restrict__ A, int lda,
    const h16* __restrict__ Bw, int ldb,
    const float* __restrict__ bias0, const float* __restrict__ bias1,
    float* __restrict__ outF, h16* __restrict__ outH, int ldc, int K)
{
  __shared__ __align__(16) h16 sA[2][4096];   // 8KB per buffer
  __shared__ __align__(16) h16 sB[2][4096];
  int tid = threadIdx.x;
  int w = tid >> 6, lane = tid & 63;
  int la = lane & 15, q = lane >> 4;
  int wr = w >> 1, wc = w & 1;
  int m0 = blockIdx.x * 128, n0 = blockIdx.y * 128;

  int srow = tid >> 2, sq = tid & 3;
  const h16* gAa = A + (size_t)(m0 + srow) * lda + sq * 8;
  const h16* gAb = gAa + (size_t)64 * lda;
  const h16* gBa = Bw + (size_t)(n0 + srow) * ldb + sq * 8;
  const h16* gBb = gBa + (size_t)64 * ldb;
  int dO = sq * 1024 + srow * 8;                 // h16 offset in [q][row] layout

  f32x4 acc[4][4];
  #pragma unroll
  for (int i = 0; i < 4; i++)
    #pragma unroll
    for (int j = 0; j < 4; j++) acc[i][j] = (f32x4){0.f, 0.f, 0.f, 0.f};

  h16x8 rAa, rAb, rBa, rBb;
  auto GLOAD = [&](int kt){
    int k0 = kt * 32;
    rAa = *reinterpret_cast<const h16x8*>(gAa + k0);
    rAb = *reinterpret_cast<const h16x8*>(gAb + k0);
    rBa = *reinterpret_cast<const h16x8*>(gBa + k0);
    rBb = *reinterpret_cast<const h16x8*>(gBb + k0);
  };
  auto SWRITE = [&](int buf){
    *reinterpret_cast<h16x8*>(&sA[buf][dO])       = rAa;
    *reinterpret_cast<h16x8*>(&sA[buf][dO + 512]) = rAb;   // rows 64..127
    *reinterpret_cast<h16x8*>(&sB[buf][dO])       = rBa;
    *reinterpret_cast<h16x8*>(&sB[buf][dO + 512]) = rBb;
  };

  int NT = K / 32;
  GLOAD(0); SWRITE(0);
  GLOAD(1);
  __syncthreads();
  for (int t = 0; t < NT; t++){
    int buf = t & 1;
    h16x8 af[4], bf[4];
    #pragma unroll
    for (int mi = 0; mi < 4; mi++)
      af[mi] = *reinterpret_cast<const h16x8*>(&sA[buf][q * 1024 + (wr * 64 + mi * 16 + la) * 8]);
    #pragma unroll
    for (int ni = 0; ni < 4; ni++)
      bf[ni] = *reinterpret_cast<const h16x8*>(&sB[buf][q * 1024 + (wc * 64 + ni * 16 + la) * 8]);
    #pragma unroll
    for (int mi = 0; mi < 4; mi++)
      #pragma unroll
      for (int ni = 0; ni < 4; ni++)
        acc[mi][ni] = __builtin_amdgcn_mfma_f32_16x16x32_f16(af[mi], bf[ni], acc[mi][ni], 0, 0, 0);
    if (t + 1 < NT){
      __syncthreads();                // everyone done reading buf[(t+1)&1] (read at t-1)
      SWRITE((t + 1) & 1);
      if (t + 2 < NT) GLOAD(t + 2);
      __syncthreads();                // writes visible before next compute
    }
  }

  #pragma unroll
  for (int mi = 0; mi < 4; mi++){
    int mrow = m0 + wr * 64 + mi * 16 + q * 4;
    #pragma unroll
    for (int ni = 0; ni < 4; ni++){
      int n = n0 + wc * 64 + ni * 16 + la;
      float bs = (bias0 ? bias0[n] : 0.f) + (bias1 ? bias1[n] : 0.f);
      #pragma unroll
      for (int r = 0; r < 4; r++){
        float v = acc[mi][ni][r] + bs;
        size_t off = (size_t)(mrow + r) * ldc + n;
        if (outF) outF[off] = v;
        else      outH[off] = (h16)v;
      }
    }
  }
}

// ---------------- 2-m-tile prefetched segment helper (kA) ----------------
struct PBuf2 { h16x8 a0, a1, b; };

__device__ __forceinline__ void pld2(PBuf2& p, const h16* __restrict__ Ap,
                                     const h16* __restrict__ Bp, int k){
  p.a0 = *reinterpret_cast<const h16x8*>(Ap + k);
  p.a1 = *reinterpret_cast<const h16x8*>(Ap + 16 * Hn + k);
  p.b  = *reinterpret_cast<const h16x8*>(Bp + k);
}
__device__ __forceinline__ void pmm2(const PBuf2& p, f32x4* acc){
  acc[0] = __builtin_amdgcn_mfma_f32_16x16x32_f16(p.a0, p.b, acc[0], 0, 0, 0);
  acc[1] = __builtin_amdgcn_mfma_f32_16x16x32_f16(p.a1, p.b, acc[1], 0, 0, 0);
}

template<int NS>
__device__ __forceinline__ void gseg2_pf(const h16* __restrict__ Ap,
                                         const h16* __restrict__ Bp, f32x4* acc){
  PBuf2 p0, p1, p2, p3;
  pld2(p0, Ap, Bp, 0);
  pld2(p1, Ap, Bp, 32);
  pld2(p2, Ap, Bp, 64);
  pld2(p3, Ap, Bp, 96);
  #pragma unroll 1
  for (int s = 0; s + 4 < NS; s += 4){
    pmm2(p0, acc); pld2(p0, Ap, Bp, (s + 4) * 32);
    pmm2(p1, acc); pld2(p1, Ap, Bp, (s + 5) * 32);
    pmm2(p2, acc); pld2(p2, Ap, Bp, (s + 6) * 32);
    pmm2(p3, acc); pld2(p3, Ap, Bp, (s + 7) * 32);
  }
  pmm2(p0, acc); pmm2(p1, acc); pmm2(p2, acc); pmm2(p3, acc);
}

// ---------------- kA: m-split + K-split. 512 threads = 8 waves = (gate g, k-half kh). ------
// mode 0 (prime, 128 blocks): all g1. mode 1 (256 blocks): bid<128 is2, bid>=128 g1.
__global__ __launch_bounds__(512, 1) void kA(
    const h16* __restrict__ h1cur, const h16* __restrict__ h2prev, const h16* __restrict__ oh,
    h16* __restrict__ h1next, h16* __restrict__ h2cur, float* __restrict__ h2f,
    float* __restrict__ c1, float* __restrict__ c2,
    const h16* __restrict__ wih2, const h16* __restrict__ whh2, const h16* __restrict__ whh1,
    const float* __restrict__ bih2, const float* __restrict__ bhh2,
    const float* __restrict__ pre1_t, int mode)
{
  __shared__ float sg[4][2][32][17];           // 17.4 KB
  int bid = blockIdx.x, tid = threadIdx.x;
  int wv = tid >> 6, lane = tid & 63;
  int g = wv & 3, kh = wv >> 2;
  int la = lane & 15, q = lane >> 4;
  bool is2 = (mode == 1) && (bid < 128);
  int unit = is2 ? bid : (mode == 1 ? bid - 128 : bid);
  int jb = unit >> 1, mh = unit & 1;
  int j0 = jb * 16;
  int r0 = mh * 32;
  bool active = is2 || (pre1_t != nullptr);

  if (active){
    f32x4 acc[2];
    acc[0] = (f32x4){0.f, 0.f, 0.f, 0.f};
    acc[1] = (f32x4){0.f, 0.f, 0.f, 0.f};
    int n0 = g * 1024 + j0;
    size_t aoff = (size_t)(r0 + la) * Hn + q * 8;
    if (is2){
      // flat K = [h1(t) | o(t-1) | h2(t-1)]; wih2 cols [0,2048), whh2 cols [0,1024)
      if (kh == 0){
        gseg2_pf<32>(h1cur + aoff, wih2 + (size_t)(n0 + la) * 2048 + q * 8,        acc);
        gseg2_pf<16>(oh    + aoff, wih2 + (size_t)(n0 + la) * 2048 + 1024 + q * 8, acc);
      } else {
        gseg2_pf<16>(oh     + aoff + 512, wih2 + (size_t)(n0 + la) * 2048 + 1536 + q * 8, acc);
        gseg2_pf<32>(h2prev + aoff,       whh2 + (size_t)(n0 + la) * 1024 + q * 8,        acc);
      }
    } else {
      if (kh == 0)
        gseg2_pf<16>(h1cur + aoff,       whh1 + (size_t)(n0 + la) * 1024 + q * 8,       acc);
      else
        gseg2_pf<16>(h1cur + aoff + 512, whh1 + (size_t)(n0 + la) * 1024 + 512 + q * 8, acc);
    }
    #pragma unroll
    for (int mi = 0; mi < 2; mi++)
      #pragma unroll
      for (int r = 0; r < 4; r++)
        sg[g][kh][mi * 16 + q * 4 + r][la] = acc[mi][r];
  }
  __syncthreads();
  if (active && tid < 512){
    int e = tid;                               // 512 elements, one per thread
    int rl = e >> 4, col = e & 15, j = j0 + col;
    int row = r0 + rl;
    float gi = sg[0][0][rl][col] + sg[0][1][rl][col];
    float gf = sg[1][0][rl][col] + sg[1][1][rl][col];
    float gg = sg[2][0][rl][col] + sg[2][1][rl][col];
    float go = sg[3][0][rl][col] + sg[3][1][rl][col];
    if (is2){
      gi += bih2[j] + bhh2[j];
      gf += bih2[j + 1024] + bhh2[j + 1024];
      gg += bih2[j + 2048] + bhh2[j + 2048];
      go += bih2[j + 3072] + bhh2[j + 3072];
      float c_ = sigf(gf) * c2[row * Hn + j] + sigf(gi) * tanhf(gg);
      c2[row * Hn + j] = c_;
      float h_ = sigf(go) * tanhf(c_);
      h2cur[row * Hn + j] = (h16)h_;
      h2f[row * Hn + j] = h_;
    } else {
      const float* p = pre1_t + (size_t)row * Gn;   // includes bih1+bhh1
      gi += p[j]; gf += p[j + 1024]; gg += p[j + 2048]; go += p[j + 3072];
      float c_ = sigf(gf) * c1[row * Hn + j] + sigf(gi) * tanhf(gg);
      c1[row * Hn + j] = c_;
      h1next[row * Hn + j] = (h16)(sigf(go) * tanhf(c_));
    }
  }
}

// ---------------- kBC-v2: e-dots + softmax + hw + gather + o_t, one launch ----------------
// 256 blocks = (b, col-quarter), 256 threads. Fixes R9: full CU coverage; gather reads the
// TRANSPOSED enc_comb (ecbt[j][b*Ln+l], contiguous 256B/thread, 4 chains); hw is a contiguous
// wcomb-row walk (4 chains, h2 in LDS); e-dots use the R8-proven 4-l-group wave pattern.
__global__ __launch_bounds__(256, 4) void kBC(
    int t, const float* __restrict__ h2f, const h16* __restrict__ eph,
    const int* __restrict__ msk, const h16* __restrict__ h2cur,
    const h16* __restrict__ wcomb, const float* __restrict__ bcomb,
    const h16* __restrict__ ecbt, float* __restrict__ out, h16* __restrict__ oh)
{
  __shared__ float se[Ln];
  __shared__ float sb[Ln];
  __shared__ float rmax[4], rsum[4];
  __shared__ __align__(16) h16 sh2[Hn];
  int bid = blockIdx.x;
  int b = bid >> 2, jq = (bid & 3) * 256;
  int tid = threadIdx.x;
  int w = tid >> 6, lane = tid & 63;

  // stage h2cur[b] (2KB): 256 threads x 8B
  reinterpret_cast<unsigned long long*>(sh2)[tid] =
      reinterpret_cast<const unsigned long long*>(h2cur + (size_t)b * Hn)[tid];

  // phase 1: e-dots; wave w covers l in [w*32, w*32+32), 4-l groups (exact R8 inner math)
  const f32x4* h2r = reinterpret_cast<const f32x4*>(h2f + (size_t)b * Hn + lane * 16);
  f32x4 hv0 = h2r[0], hv1 = h2r[1], hv2 = h2r[2], hv3 = h2r[3];
  for (int gse = 0; gse < 8; gse++){
    int l0 = w * 32 + gse * 4;
    #pragma unroll
    for (int li = 0; li < 4; li++){
      int l = l0 + li;
      const h16x8* er = reinterpret_cast<const h16x8*>(eph + ((size_t)b * Ln + l) * Hn + lane * 16);
      h16x8 e0 = er[0], e1 = er[1];
      float acc = 0.f;
      #pragma unroll
      for (int i = 0; i < 4; i++) acc += hv0[i] * (float)e0[i];
      #pragma unroll
      for (int i = 0; i < 4; i++) acc += hv1[i] * (float)e0[4 + i];
      #pragma unroll
      for (int i = 0; i < 4; i++) acc += hv2[i] * (float)e1[i];
      #pragma unroll
      for (int i = 0; i < 4; i++) acc += hv3[i] * (float)e1[4 + i];
      for (int off = 32; off; off >>= 1) acc += __shfl_xor(acc, off);
      if (lane == 0) se[l] = msk[b * Ln + l] ? -1e30f : acc;
    }
  }
  __syncthreads();

  // phase 2: softmax (R11 kC shuffle pattern; waves 2,3 duplicate waves 0,1 via tid&127)
  float e = se[tid & 127];
  float m = e;
  #pragma unroll
  for (int off = 32; off; off >>= 1) m = fmaxf(m, __shfl_xor(m, off));
  if ((tid & 63) == 0) rmax[w] = m;
  __syncthreads();
  m = fmaxf(fmaxf(rmax[0], rmax[1]), fmaxf(rmax[2], rmax[3]));
  float ex = expf(e - m);
  if (tid < 128) sb[tid] = ex;
  float s = ex;
  #pragma unroll
  for (int off = 32; off; off >>= 1) s += __shfl_xor(s, off);
  if ((tid & 63) == 0) rsum[w] = s;
  __syncthreads();
  float rinv = 1.f / (rsum[0] + rsum[1]);   // waves 2,3 are duplicates — excluded

  // phase 3: per thread, one output col j. hw: contiguous wcomb row, 4 chains, h2 from LDS.
  int j = jq + tid;
  const h16x8* wr_ = reinterpret_cast<const h16x8*>(wcomb + (size_t)j * (HEn + Hn) + HEn);
  const h16x8* hh  = reinterpret_cast<const h16x8*>(sh2);
  float hc0 = 0.f, hc1 = 0.f, hc2 = 0.f, hc3 = 0.f;
  #pragma unroll 4
  for (int i = 0; i < 128; i += 4){
    hc0 += dot8f(wr_[i],     hh[i]);
    hc1 += dot8f(wr_[i + 1], hh[i + 1]);
    hc2 += dot8f(wr_[i + 2], hh[i + 2]);
    hc3 += dot8f(wr_[i + 3], hh[i + 3]);
  }
  float hw = hc0 + hc1 + hc2 + hc3 + bcomb[j];

  // phase 4: gather from transposed enc_comb: 16 contiguous h16x8 loads, 4 chains.
  const h16x8* gr = reinterpret_cast<const h16x8*>(ecbt + (size_t)j * (Bn * Ln) + b * Ln);
  float gc0 = 0.f, gc1 = 0.f, gc2 = 0.f, gc3 = 0.f;
  #pragma unroll
  for (int i = 0; i < 16; i += 4){
    h16x8 v0 = gr[i], v1 = gr[i + 1], v2 = gr[i + 2], v3 = gr[i + 3];
    float p0 = 0.f, p1 = 0.f, p2 = 0.f, p3 = 0.f;
    #pragma unroll
    for (int e2 = 0; e2 < 8; e2++){
      p0 += (float)v0[e2] * sb[i * 8 + e2];
      p1 += (float)v1[e2] * sb[i * 8 + 8 + e2];
      p2 += (float)v2[e2] * sb[i * 8 + 16 + e2];
      p3 += (float)v3[e2] * sb[i * 8 + 24 + e2];
    }
    gc0 += p0; gc1 += p1; gc2 += p2; gc3 += p3;
  }
  float g = (gc0 + gc1 + gc2 + gc3) * rinv;

  float o = tanhf(g + hw);
  out[((size_t)t * Bn + b) * Hn + j] = o;
  oh[(size_t)b * Hn + j] = (h16)o;
}

// ---------------- host ----------------
extern "C" void kernel_launch(void* const* d_in, const int* in_sizes, int n_in,
                              void* d_out, int out_size, void* d_ws, size_t ws_size,
                              hipStream_t stream)
{
  const float* enc   = (const float*)d_in[0];
  const int*   msk   = (const int*)  d_in[1];
  const float* h1i   = (const float*)d_in[2];
  const float* c1i   = (const float*)d_in[3];
  const float* h2i   = (const float*)d_in[4];
  const float* c2i   = (const float*)d_in[5];
  const float* caps  = (const float*)d_in[6];
  const float* Wih1  = (const float*)d_in[7];
  const float* Whh1  = (const float*)d_in[8];
  const float* bih1  = (const float*)d_in[9];
  const float* bhh1  = (const float*)d_in[10];
  const float* Wih2  = (const float*)d_in[11];
  const float* Whh2  = (const float*)d_in[12];
  const float* bih2  = (const float*)d_in[13];
  const float* bhh2  = (const float*)d_in[14];
  const float* Watt  = (const float*)d_in[15];
  const float* batt  = (const float*)d_in[16];
  const float* Wcomb = (const float*)d_in[17];
  const float* bcomb = (const float*)d_in[18];
  float* out = (float*)d_out;

  char* p = (char*)d_ws;
  auto take = [&](size_t bytes){ char* r = p; p += (bytes + 255) & ~(size_t)255; return r; };
  float* pre1   = (float*)take((size_t)Tn * Bn * Gn * 4);          // 50.3 MB
  h16*   ench   = (h16*)take((size_t)Bn * Ln * HEn * 2);
  h16*   eph    = (h16*)take((size_t)Bn * Ln * Hn * 2);
  h16*   ecbt   = (h16*)take((size_t)Hn * Bn * Ln * 2);            // transposed enc_comb
  h16*   caph   = (h16*)take((size_t)Tn * Bn * En * 2);
  h16*   wih1h  = (h16*)take((size_t)Gn * En * 2);
  h16*   whh1h  = (h16*)take((size_t)Gn * Hn * 2);
  h16*   wih2h  = (h16*)take((size_t)Gn * 2 * Hn * 2);
  h16*   whh2h  = (h16*)take((size_t)Gn * Hn * 2);
  h16*   watth  = (h16*)take((size_t)Hn * HEn * 2);
  h16*   wcombh = (h16*)take((size_t)Hn * (HEn + Hn) * 2);
  h16*   h1b0   = (h16*)take((size_t)Bn * Hn * 2);
  h16*   h1b1   = (h16*)take((size_t)Bn * Hn * 2);
  h16*   h2b0   = (h16*)take((size_t)Bn * Hn * 2);
  h16*   h2b1   = (h16*)take((size_t)Bn * Hn * 2);
  h16*   oh     = (h16*)take((size_t)Bn * Hn * 2);
  float* c1     = (float*)take((size_t)Bn * Hn * 4);
  float* c2     = (float*)take((size_t)Bn * Hn * 4);
  float* h2f    = (float*)take((size_t)Bn * Hn * 4);
  (void)ws_size; (void)n_in; (void)in_sizes; (void)out_size;

  auto cvt = [&](const float* src, void* dst, int n){
    int n2 = n / 2;
    int blocks = (n2 + 255) / 256; if (blocks > 2048) blocks = 2048;
    cvt2<<<blocks, 256, 0, stream>>>(src, (h16x2*)dst, n2);
  };
  cvt(enc,   ench,   Bn * Ln * HEn);
  cvt(caps,  caph,   Tn * Bn * En);
  cvt(Wih1,  wih1h,  Gn * En);
  cvt(Whh1,  whh1h,  Gn * Hn);
  cvt(Wih2,  wih2h,  Gn * 2 * Hn);
  cvt(Whh2,  whh2h,  Gn * Hn);
  cvt(Watt,  watth,  Hn * HEn);
  cvt(Wcomb, wcombh, Hn * (HEn + Hn));

  init_state<<<(Bn * Hn) / 256, 256, 0, stream>>>(h1i, c1i, h2i, c2i,
                                                  h1b0, c1, h2b0, c2, h2f, oh);

  // pre1 = captions @ Wih1^T + bih1 + bhh1   (3072 x 4096, K=512)
  gemm_lds<<<dim3((Tn * Bn) / 128, Gn / 128), 256, 0, stream>>>(
      caph, En, wih1h, En, bih1, bhh1, pre1, nullptr, Gn, En);
  // enc_proj = enc @ Watt^T + batt  (8192 x 1024, K=1024) -> fp16
  gemm_lds<<<dim3((Bn * Ln) / 128, Hn / 128), 256, 0, stream>>>(
      ench, HEn, watth, HEn, batt, nullptr, nullptr, eph, Hn, HEn);
  // ecbt[j][bl] = dot(Wcomb[j,:HE], enc[bl,:])  (1024 x 8192, K=1024) -> fp16, transposed
  gemm_lds<<<dim3(Hn / 128, (Bn * Ln) / 128), 256, 0, stream>>>(
      wcombh, HEn + Hn, ench, HEn, nullptr, nullptr, nullptr, ecbt, Bn * Ln, HEn);

  // prime: gates1(0) -> h1(0) in h1b1 (h1 state for t lives in h1buf[(t+1)&1])
  kA<<<128, 512, 0, stream>>>(h1b0, h2b0, oh, h1b1, h2b1, h2f, c1, c2,
                              wih2h, whh2h, whh1h, bih2, bhh2, pre1, /*mode=*/0);

  h16* h1buf[2] = { h1b0, h1b1 };
  h16* h2buf[2] = { h2b0, h2b1 };
  for (int t = 0; t < Tn; t++){
    h16* h1cur  = h1buf[(t + 1) & 1];
    h16* h1next = h1buf[t & 1];
    h16* h2prev = h2buf[t & 1];
    h16* h2cur  = h2buf[(t + 1) & 1];
    const float* pre1_t = (t + 1 < Tn) ? (pre1 + (size_t)(t + 1) * Bn * Gn) : nullptr;
    kA<<<256, 512, 0, stream>>>(h1cur, h2prev, oh, h1next, h2cur, h2f, c1, c2,
                                wih2h, whh2h, whh1h, bih2, bhh2, pre1_t, /*mode=*/1);
    kBC<<<256, 256, 0, stream>>>(t, h2f, eph, msk, h2cur, wcombh, bcomb, ecbt, out, oh);
  }
}